// Round 12
// baseline (39.989 us; speedup 1.0000x reference)
//
#include <hip/hip_runtime.h>

#define BATCH 256
#define ZTILE 16          // z per LDS tile
#define NZT 2             // tiles per block -> 32 z per block; grid.y = 8
#define PADF 20           // floats per stripe (16 z + 4 pad) = 80 B; spreads bank starts
#define DIN_CAP 416       // dim_in for this problem

typedef float __attribute__((ext_vector_type(2))) fx2;   // native vec2 for nt-store

// ---------------- prep: tiled transpose f->fT + COO segment-bounds scatter ----
__global__ __launch_bounds__(256) void prep_t(
    const float* __restrict__ f, const int* __restrict__ rows,
    int* __restrict__ rstart, int* __restrict__ rend,
    float* __restrict__ fT, int nnz, int dim_in, int TB, int ctiles)
{
    const int bx = blockIdx.x;
    if (bx < TB) {
        __shared__ float lt[32][33];
        const int c0 = (bx % ctiles) * 32;
        const int z0 = (bx / ctiles) * 32;
        const int ic = threadIdx.x & 31;
        const int i0 = threadIdx.x >> 5;          // 0..7
#pragma unroll
        for (int k = 0; k < 4; ++k) {             // lt[a][b] = f[z0+a][c0+b]
            const int a = i0 + 8 * k;
            const int c = c0 + ic;
            lt[a][ic] = (c < dim_in) ? f[(size_t)(z0 + a) * dim_in + c] : 0.0f;
        }
        __syncthreads();
#pragma unroll
        for (int k = 0; k < 4; ++k) {             // fT[c0+b][z0+a], lane->z
            const int b = i0 + 8 * k;
            const int c = c0 + b;
            if (c < dim_in)
                fT[(size_t)c * BATCH + z0 + ic] = lt[ic][b];
        }
    } else {
        const int e = (bx - TB) * 256 + threadIdx.x;
        if (e < nnz) {
            const int r = rows[e];
            if (e == 0 || rows[e - 1] != r) rstart[r] = e;
            if (e == nnz - 1 || rows[e + 1] != r) rend[r] = e + 1;
        }
    }
}

// Barrier that waits only on LDS ops (lgkmcnt), leaving HBM stores in flight.
__device__ __forceinline__ void lds_sync()
{
    asm volatile("s_waitcnt lgkmcnt(0)" ::: "memory");
    __builtin_amdgcn_sched_barrier(0);
    __builtin_amdgcn_s_barrier();
    __builtin_amdgcn_sched_barrier(0);
}

// Thread = (2 consecutive rows, 16 z): 8B stores (512B/wave-inst),
// 4 independent gather chains per tile.
__global__ __launch_bounds__(256) void tsq_main2(
    const float* __restrict__ fT, const float* __restrict__ vals,
    const int* __restrict__ ci, const int* __restrict__ cj,
    const int* __restrict__ rstart, const int* __restrict__ rend,
    float* __restrict__ out, int dim_in, int dim_out, int nnz)
{
    __shared__ __align__(16) float fzT[DIN_CAP * PADF];   // 33280 B -> 4 blocks/CU

    const int r0 = (blockIdx.x * blockDim.x + threadIdx.x) * 2;
    const bool valid = (r0 + 1 < dim_out);   // dim_out even -> pairs complete

    int s0 = 0, e0 = 0, s1 = 0, e1 = 0;
    if (valid) {
        const int2 ss = *(const int2*)(rstart + r0);   // coalesced 8B
        const int2 ee = *(const int2*)(rend + r0);
        if (ss.x >= 0 && ee.x > ss.x && ee.x <= nnz) { s0 = ss.x; e0 = ee.x; }
        if (ss.y >= 0 && ee.y > ss.y && ee.y <= nnz) { s1 = ss.y; e1 = ee.y; }
    }

    const int zbase = blockIdx.y * (ZTILE * NZT);
    const int nchunk = dim_in * (ZTILE / 4);   // float4 chunks per stage

    for (int t = 0; t < NZT; ++t) {
        const int z0 = zbase + t * ZTILE;

        // stage fzT[c][0..15] = fT[c][z0..z0+15]; float4 both sides
        for (int i = threadIdx.x; i < nchunk; i += blockDim.x) {
            const int c  = i >> 2;
            const int zq = i & 3;
            const float4 v = *(const float4*)(fT + (size_t)c * BATCH + z0 + zq * 4);
            *(float4*)(fzT + c * PADF + zq * 4) = v;
        }
        lds_sync();   // ds_writes visible; previous tile's stores stay in flight

        float4 A0 = {0,0,0,0}, A1 = {0,0,0,0}, A2 = {0,0,0,0}, A3 = {0,0,0,0};
        float4 B0 = {0,0,0,0}, B1 = {0,0,0,0}, B2 = {0,0,0,0}, B3 = {0,0,0,0};

        for (int e = s0; e < e0; ++e) {        // row r0
            const int   a = ci[e];
            const int   b = cj[e];
            const float v = vals[e];
            const float* ba = fzT + a * PADF;
            const float* bb = fzT + b * PADF;
            float4 xa, xb;
            xa = *(const float4*)(ba);      xb = *(const float4*)(bb);
            A0.x += v*xa.x*xb.x; A0.y += v*xa.y*xb.y; A0.z += v*xa.z*xb.z; A0.w += v*xa.w*xb.w;
            xa = *(const float4*)(ba + 4);  xb = *(const float4*)(bb + 4);
            A1.x += v*xa.x*xb.x; A1.y += v*xa.y*xb.y; A1.z += v*xa.z*xb.z; A1.w += v*xa.w*xb.w;
            xa = *(const float4*)(ba + 8);  xb = *(const float4*)(bb + 8);
            A2.x += v*xa.x*xb.x; A2.y += v*xa.y*xb.y; A2.z += v*xa.z*xb.z; A2.w += v*xa.w*xb.w;
            xa = *(const float4*)(ba + 12); xb = *(const float4*)(bb + 12);
            A3.x += v*xa.x*xb.x; A3.y += v*xa.y*xb.y; A3.z += v*xa.z*xb.z; A3.w += v*xa.w*xb.w;
        }
        for (int e = s1; e < e1; ++e) {        // row r0+1
            const int   a = ci[e];
            const int   b = cj[e];
            const float v = vals[e];
            const float* ba = fzT + a * PADF;
            const float* bb = fzT + b * PADF;
            float4 xa, xb;
            xa = *(const float4*)(ba);      xb = *(const float4*)(bb);
            B0.x += v*xa.x*xb.x; B0.y += v*xa.y*xb.y; B0.z += v*xa.z*xb.z; B0.w += v*xa.w*xb.w;
            xa = *(const float4*)(ba + 4);  xb = *(const float4*)(bb + 4);
            B1.x += v*xa.x*xb.x; B1.y += v*xa.y*xb.y; B1.z += v*xa.z*xb.z; B1.w += v*xa.w*xb.w;
            xa = *(const float4*)(ba + 8);  xb = *(const float4*)(bb + 8);
            B2.x += v*xa.x*xb.x; B2.y += v*xa.y*xb.y; B2.z += v*xa.z*xb.z; B2.w += v*xa.w*xb.w;
            xa = *(const float4*)(ba + 12); xb = *(const float4*)(bb + 12);
            B3.x += v*xa.x*xb.x; B3.y += v*xa.y*xb.y; B3.z += v*xa.z*xb.z; B3.w += v*xa.w*xb.w;
        }

        if (valid) {   // 16 fx2 nt stores (8B-aligned: dim_out even), 512B/wave
            float* o = out + (size_t)z0 * dim_out + r0;
            const size_t d = dim_out;
            fx2 w;
            w.x=A0.x; w.y=B0.x; __builtin_nontemporal_store(w, (fx2*)(o));
            w.x=A0.y; w.y=B0.y; __builtin_nontemporal_store(w, (fx2*)(o + d));
            w.x=A0.z; w.y=B0.z; __builtin_nontemporal_store(w, (fx2*)(o + 2*d));
            w.x=A0.w; w.y=B0.w; __builtin_nontemporal_store(w, (fx2*)(o + 3*d));
            w.x=A1.x; w.y=B1.x; __builtin_nontemporal_store(w, (fx2*)(o + 4*d));
            w.x=A1.y; w.y=B1.y; __builtin_nontemporal_store(w, (fx2*)(o + 5*d));
            w.x=A1.z; w.y=B1.z; __builtin_nontemporal_store(w, (fx2*)(o + 6*d));
            w.x=A1.w; w.y=B1.w; __builtin_nontemporal_store(w, (fx2*)(o + 7*d));
            w.x=A2.x; w.y=B2.x; __builtin_nontemporal_store(w, (fx2*)(o + 8*d));
            w.x=A2.y; w.y=B2.y; __builtin_nontemporal_store(w, (fx2*)(o + 9*d));
            w.x=A2.z; w.y=B2.z; __builtin_nontemporal_store(w, (fx2*)(o + 10*d));
            w.x=A2.w; w.y=B2.w; __builtin_nontemporal_store(w, (fx2*)(o + 11*d));
            w.x=A3.x; w.y=B3.x; __builtin_nontemporal_store(w, (fx2*)(o + 12*d));
            w.x=A3.y; w.y=B3.y; __builtin_nontemporal_store(w, (fx2*)(o + 13*d));
            w.x=A3.z; w.y=B3.z; __builtin_nontemporal_store(w, (fx2*)(o + 14*d));
            w.x=A3.w; w.y=B3.w; __builtin_nontemporal_store(w, (fx2*)(o + 15*d));
        }
        lds_sync();   // all waves' ds_reads done -> safe to restage
    }
}

// Fallback (odd dim_out, big dim_in, or tiny workspace): reads f directly.
__global__ __launch_bounds__(256) void tsq_fallback(
    const float* __restrict__ f, const float* __restrict__ vals,
    const int* __restrict__ ci, const int* __restrict__ cj,
    const int* __restrict__ rstart, const int* __restrict__ rend,
    float* __restrict__ out, int dim_in, int dim_out, int nnz)
{
    const int r = blockIdx.x * blockDim.x + threadIdx.x;
    if (r >= dim_out) return;
    const int z = blockIdx.y;
    const float* __restrict__ fb = f + (size_t)z * dim_in;
    const int ss = rstart[r];
    const int ee = rend[r];
    float acc = 0.0f;
    if (ss >= 0 && ee > ss && ee <= nnz) {
        for (int e = ss; e < ee; ++e)
            acc += vals[e] * fb[ci[e]] * fb[cj[e]];
    }
    out[(size_t)z * dim_out + r] = acc;
}

extern "C" void kernel_launch(void* const* d_in, const int* in_sizes, int n_in,
                              void* d_out, int out_size, void* d_ws, size_t ws_size,
                              hipStream_t stream)
{
    const float* f    = (const float*)d_in[0];
    const float* vals = (const float*)d_in[1];
    const int*   rows = (const int*)d_in[2];
    const int*   ci   = (const int*)d_in[3];
    const int*   cj   = (const int*)d_in[4];
    float*       out  = (float*)d_out;

    const int nnz     = in_sizes[1];
    const int nF      = in_sizes[0];
    const int dim_in  = nF / BATCH;
    const int dim_out = out_size / BATCH;

    int*   rstart = (int*)d_ws;
    int*   rend   = rstart + dim_out;
    float* fT     = (float*)(rend + dim_out);

    const int use_main = (dim_in <= DIN_CAP) && ((dim_out & 1) == 0) &&
                         (ws_size >= (size_t)(2 * dim_out) * 4 + (size_t)nF * 4);

    const int ctiles = (dim_in + 31) / 32;
    const int TB = use_main ? ctiles * (BATCH / 32) : 0;   // transpose tile blocks
    const int NB = (nnz + 255) / 256;                      // bounds blocks
    prep_t<<<TB + NB, 256, 0, stream>>>(f, rows, rstart, rend, fT,
                                        nnz, dim_in, TB, ctiles);

    if (use_main) {
        const int rpairs = dim_out / 2;
        dim3 grid((rpairs + 255) / 256, BATCH / (ZTILE * NZT));
        tsq_main2<<<grid, 256, 0, stream>>>(fT, vals, ci, cj, rstart, rend, out,
                                            dim_in, dim_out, nnz);
    } else {
        dim3 grid((dim_out + 255) / 256, BATCH);
        tsq_fallback<<<grid, 256, 0, stream>>>(f, vals, ci, cj, rstart, rend,
                                               out, dim_in, dim_out, nnz);
    }
}